// Round 8
// baseline (134.095 us; speedup 1.0000x reference)
//
#include <hip/hip_runtime.h>

// CRF loss forward, chunked log-semiring matrix-product formulation (register-direct v4).
// scores (512,128,48,48) f32, target (512,128) int32, mask (512,128) int32 -> scalar f32
//
// Phase 1: 4096 independent waves (CHUNK=16); wave (c,b) computes prod of 16
//   exp-space transition matrices from an EXACT identity B. K=48 split as
//   32 (mfma 16x16x32) + 16 (mfma 16x16x16). Per-step scale 2^-7 exact
//   (incl. identity steps) -> correction 512*7*ln2. Products stored bf16.
// Phase 2: per-batch fold of 32 bf16 chunk matrices; absorbs per-batch tg sum,
//   writes val_b = logZ_b - tg_b. Phase 3: single-wave 128-float reduce.

#define S_LEN 512
#define BATCH 128
#define T 48
#define TT 2304
#define START_TAG 46
#define END_TAG 47

#define CHUNK 16
#define NCHUNK 32
#define NTASK (NCHUNK * BATCH)       // 4096
#define P1_WAVES 4
#define P1_THREADS 256
#define P1_BLOCKS (NTASK / P1_WAVES) // 1024
#define SIGMA 0.0078125f             // 2^-7

typedef float f32x4 __attribute__((ext_vector_type(4)));
typedef short bf16x8 __attribute__((ext_vector_type(8)));
typedef short bf16x4 __attribute__((ext_vector_type(4)));

__device__ __forceinline__ short f2bf(float x) {  // RTNE f32->bf16 bits
  unsigned u = __float_as_uint(x);
  u = (u + 0x7fffu + ((u >> 16) & 1u)) >> 16;
  return (short)u;
}

#if __has_builtin(__builtin_amdgcn_exp2f)
#define EXPS(x) __builtin_amdgcn_exp2f(fmaf((x), 1.44269504089f, -7.0f))
#else
#define EXPS(x) (__expf(x) * SIGMA)
#endif

#if __has_builtin(__builtin_amdgcn_mfma_f32_16x16x16bf16_1k)
#define MFMA16(a, b, c) __builtin_amdgcn_mfma_f32_16x16x16bf16_1k((a), (b), (c), 0, 0, 0)
#else
static __device__ __forceinline__ f32x4 mfma16_asm(bf16x4 a, bf16x4 b, f32x4 c) {
  f32x4 d;
  asm volatile("v_mfma_f32_16x16x16_bf16 %0, %1, %2, %3\n\ts_nop 7"
               : "=v"(d) : "v"(a), "v"(b), "v"(c));
  return d;
}
#define MFMA16(a, b, c) mfma16_asm((a), (b), (c))
#endif

struct Raw { float r24[24]; float r12[12]; };

// load matrix k's A-fragment raw f32 values (36/lane, coalesced 64B segments)
#define CRF_LOAD(RW, PE) do {                                                  \
  const float* q0_ = (PE) + (size_t)(8 * g) * T + c15;                         \
  _Pragma("unroll") for (int ti = 0; ti < 3; ++ti)                             \
    _Pragma("unroll") for (int i = 0; i < 8; ++i)                              \
      (RW).r24[ti * 8 + i] = q0_[(size_t)i * T + 16 * ti];                     \
  const float* q1_ = (PE) + (size_t)(32 + 4 * g) * T + c15;                    \
  _Pragma("unroll") for (int ti = 0; ti < 3; ++ti)                             \
    _Pragma("unroll") for (int i = 0; i < 4; ++i)                              \
      (RW).r12[ti * 4 + i] = q1_[(size_t)i * T + 16 * ti];                     \
} while (0)

// one product step: A = sigma*E^T (or sigma*I if masked or global step 0);
// Cf = A32.B32 + A16.B16; then recycle Cf -> (Bf32, Bf16).
#define CRF_STEP(RW, KK, RECYC) do {                                           \
  const int msk_ = __shfl(mt, (KK), 64);                                       \
  const bool id_ = (msk_ == 0) || ((s0 == 0) && ((KK) == 0));                  \
  bf16x8 A32_[3]; bf16x4 A16_[3];                                              \
  _Pragma("unroll") for (int ti = 0; ti < 3; ++ti) {                           \
    bf16x8 av_;                                                                \
    _Pragma("unroll") for (int i = 0; i < 8; ++i) {                            \
      float v_ = id_ ? (((8 * g + i) == (16 * ti + c15)) ? SIGMA : 0.f)        \
                     : EXPS((RW).r24[ti * 8 + i]);                             \
      av_[i] = f2bf(v_);                                                       \
    }                                                                          \
    A32_[ti] = av_;                                                            \
    bf16x4 aw_;                                                                \
    _Pragma("unroll") for (int i = 0; i < 4; ++i) {                            \
      float v_ = id_ ? (((32 + 4 * g + i) == (16 * ti + c15)) ? SIGMA : 0.f)   \
                     : EXPS((RW).r12[ti * 4 + i]);                             \
      aw_[i] = f2bf(v_);                                                       \
    }                                                                          \
    A16_[ti] = aw_;                                                            \
  }                                                                            \
  _Pragma("unroll") for (int ti = 0; ti < 3; ++ti)                             \
    _Pragma("unroll") for (int tj = 0; tj < 3; ++tj)                           \
      Cf[ti][tj] = __builtin_amdgcn_mfma_f32_16x16x32_bf16(A32_[ti], Bf32[tj], zz, 0, 0, 0); \
  _Pragma("unroll") for (int ti = 0; ti < 3; ++ti)                             \
    _Pragma("unroll") for (int tj = 0; tj < 3; ++tj)                           \
      Cf[ti][tj] = MFMA16(A16_[ti], Bf16[tj], Cf[ti][tj]);                     \
  if (RECYC) {                                                                 \
    _Pragma("unroll") for (int tj = 0; tj < 3; ++tj) {                         \
      bf16x8 b0_; bf16x4 b1_;                                                  \
      const int sLo_ = ((g & 1) << 5) + c15;                                   \
      _Pragma("unroll") for (int i = 0; i < 8; ++i) {                          \
        const int r_ = i & 3;                                                  \
        const int s_ = sLo_ + ((i & 4) ? 16 : 0);                              \
        float a0_ = __shfl(Cf[0][tj][r_], s_, 64);                             \
        float a1_ = __shfl(Cf[1][tj][r_], s_, 64);                             \
        b0_[i] = f2bf((g >> 1) ? a1_ : a0_);                                   \
      }                                                                        \
      _Pragma("unroll") for (int i = 0; i < 4; ++i) b1_[i] = f2bf(Cf[2][tj][i]); \
      Bf32[tj] = b0_; Bf16[tj] = b1_;                                          \
    }                                                                          \
  }                                                                            \
} while (0)

// ---------------- Phase 1: per-chunk matrix product ----------------
__global__ __launch_bounds__(P1_THREADS, 2) void crf_chunk(
    const float* __restrict__ scores, const int* __restrict__ target,
    const int* __restrict__ mask, unsigned short* __restrict__ Rbuf,
    float* __restrict__ tgbuf)
{
  const int t = threadIdx.x;
  const int lane = t & 63;
  const int wid = t >> 6;
  const int g = lane >> 4;    // 0..3
  const int c15 = lane & 15;  // 0..15

  const int task = blockIdx.x * P1_WAVES + wid;
  const int b = task & (BATCH - 1);
  const int cIdx = task >> 7;
  const int s0 = cIdx * CHUNK;

  // mask (lanes 0..31, dup x2) / target (lanes 32..63, dup x2) for this chunk
  int mt;
  {
    int sl = s0 + (lane & (CHUNK - 1));
    mt = (lane < 32) ? mask[(size_t)sl * BATCH + b]
                     : target[(size_t)sl * BATCH + b];
  }

  // tg gather: lane k (k<CHUNK) loads scores[s0+k][b][tgt_k] -- all steps CONCURRENT
  float tg = 0.f;
  {
    int tgt_l = __shfl(mt, 32 + (lane & 31), 64);
    if (lane < CHUNK && mt)  // lane<CHUNK: mt == mask[s0+lane]
      tg = scores[((size_t)(s0 + lane) * BATCH + b) * TT + tgt_l];
  }

  const float* sb0 = scores + ((size_t)s0 * BATCH + b) * TT;
  const size_t mstride = (size_t)BATCH * TT;

  // prefetch raws for k=0 immediately
  Raw rA, rB;
  CRF_LOAD(rA, sb0);

  // ---- B init = EXACT identity (bf16 1.0 at kk==col)
  bf16x8 Bf32[3];
  bf16x4 Bf16[3];
#pragma unroll
  for (int tj = 0; tj < 3; ++tj) {
    const int col = 16 * tj + c15;
    bf16x8 bv;
#pragma unroll
    for (int i = 0; i < 8; ++i) bv[i] = ((8 * g + i) == col) ? (short)0x3F80 : (short)0;
    Bf32[tj] = bv;
    bf16x4 bw;
#pragma unroll
    for (int i = 0; i < 4; ++i) bw[i] = ((32 + 4 * g + i) == col) ? (short)0x3F80 : (short)0;
    Bf16[tj] = bw;
  }

  f32x4 Cf[3][3];
  const f32x4 zz = {0.f, 0.f, 0.f, 0.f};

  // software-pipelined x2: CHUNK steps total (k = 0..CHUNK-1)
  int k = 0;
#pragma unroll 1
  for (; k + 2 < CHUNK; k += 2) {
    CRF_LOAD(rB, sb0 + (size_t)(k + 1) * mstride);
    CRF_STEP(rA, k, 1);
    CRF_LOAD(rA, sb0 + (size_t)(k + 2) * mstride);
    CRF_STEP(rB, k + 1, 1);
  }
  // tail: steps CHUNK-2, CHUNK-1
  CRF_LOAD(rB, sb0 + (size_t)(CHUNK - 1) * mstride);
  CRF_STEP(rA, CHUNK - 2, 1);
  CRF_STEP(rB, CHUNK - 1, 0);

  // write chunk product R^T (48x48, row-major [j][i]) as bf16
  unsigned short* outp = Rbuf + (size_t)((size_t)cIdx * BATCH + b) * TT;
#pragma unroll
  for (int ti = 0; ti < 3; ++ti)
#pragma unroll
    for (int tj = 0; tj < 3; ++tj)
#pragma unroll
      for (int r = 0; r < 4; ++r) {
        int j = 16 * ti + 4 * g + r;
        int icol = 16 * tj + c15;
        outp[j * T + icol] = (unsigned short)f2bf(Cf[ti][tj][r]);
      }

  // reduce tg across lanes (lanes >= CHUNK hold 0)
#pragma unroll
  for (int d = 1; d < 64; d <<= 1) tg += __shfl_xor(tg, d, 64);
  if (lane == 0) tgbuf[task] = tg;
}

// ---------------- Phase 2: per-batch fold over 32 bf16 chunk matrices ----------------
// Also absorbs the per-batch tg reduction; writes val_b = logZ_b - tg_b.
__global__ __launch_bounds__(64) void crf_fold(
    const float* __restrict__ scores, const unsigned short* __restrict__ Rbuf,
    const float* __restrict__ tgbuf, float* __restrict__ vals)
{
  __shared__ __align__(16) float e[T];
  const int b = blockIdx.x;
  const int j = threadIdx.x & 63;
  const int jr = (j < T) ? j : (T - 1);
  float p = (j < T) ? scores[(size_t)b * TT + START_TAG * T + j] : -1e30f;

  // per-batch tg partial: lane c (c < NCHUNK) reads tgbuf[c*BATCH + b]
  float tgsum = (j < NCHUNK) ? tgbuf[(size_t)j * BATCH + b] : 0.f;

  // row j of chunk c: 48 bf16 = 96 B = 6 x uint4 (aligned: 4608*idx + 96*jr)
  uint4 bufA[6], bufB[6];
  {
    const uint4* rA = (const uint4*)(Rbuf + ((size_t)0 * BATCH + b) * TT + (size_t)jr * T);
#pragma unroll
    for (int q = 0; q < 6; ++q) bufA[q] = rA[q];
  }

#define FOLD_STEP(BUF) do {                                                    \
    float sh = __shfl(p, 0, 64);                                               \
    float ev = __expf(p - sh);                                                 \
    if (j < T) e[j] = ev;                                                      \
    asm volatile("s_waitcnt lgkmcnt(0)" ::: "memory");                         \
    __syncthreads();                                                           \
    float acc = 0.f;                                                           \
    _Pragma("unroll") for (int q = 0; q < 6; ++q) {                            \
      const unsigned* u = (const unsigned*)&(BUF)[q];                          \
      _Pragma("unroll") for (int h = 0; h < 4; ++h) {                          \
        float lo = __uint_as_float(u[h] << 16);                                \
        float hi = __uint_as_float(u[h] & 0xffff0000u);                        \
        acc += e[q * 8 + 2 * h] * lo;                                          \
        acc += e[q * 8 + 2 * h + 1] * hi;                                      \
      }                                                                        \
    }                                                                          \
    p = sh + __logf(acc);                                                      \
    __syncthreads();                                                           \
  } while (0)

#pragma unroll 1
  for (int c = 0; c < NCHUNK; c += 2) {
    const uint4* rB = (const uint4*)(Rbuf + ((size_t)(c + 1) * BATCH + b) * TT + (size_t)jr * T);
#pragma unroll
    for (int q = 0; q < 6; ++q) bufB[q] = rB[q];
    FOLD_STEP(bufA);
    if (c + 2 < NCHUNK) {
      const uint4* rA = (const uint4*)(Rbuf + ((size_t)(c + 2) * BATCH + b) * TT + (size_t)jr * T);
#pragma unroll
      for (int q = 0; q < 6; ++q) bufA[q] = rA[q];
    }
    FOLD_STEP(bufB);
  }
#undef FOLD_STEP

  // reduce tgsum across lanes (fixed order), fetch logZ from lane END_TAG
#pragma unroll
  for (int d = 1; d < 64; d <<= 1) tgsum += __shfl_xor(tgsum, d, 64);
  float pEnd = __shfl(p, END_TAG, 64);
  if (j == 0) vals[b] = pEnd - tgsum;
}

// ---------------- Phase 3: deterministic single-wave reduce ----------------
__global__ void crf_final(const float* __restrict__ vals, float* __restrict__ out)
{
  const int lane = threadIdx.x & 63;
  float v = vals[lane] + vals[64 + lane];
#pragma unroll
  for (int d = 1; d < 64; d <<= 1) v += __shfl_xor(v, d, 64);
  if (lane == 0) {
    // 512 steps, each scaled by exactly 2^-7 -> 512*7*ln2
    const float corr = 3584.0f * 0.6931471805599453f;
    out[0] = v / (float)BATCH + corr;
  }
}

// ---------------- Fallback (proven round-1 scan) for small ws ----------------
__global__ __launch_bounds__(512) void fb_scan(
    const float* __restrict__ scores, const int* __restrict__ target,
    const int* __restrict__ mask, float* __restrict__ ws)
{
  __shared__ float tile[2][TT];
  __shared__ float p[T];
  __shared__ float red_m[8][T];
  __shared__ float red_s[8][T];
  __shared__ int lmask[S_LEN];
  __shared__ int ltgt[S_LEN];

  const int b = blockIdx.x;
  const int t = threadIdx.x;
  const int j = t & 63;
  const int ic = t >> 6;
  const bool valid = (j < T);

  lmask[t] = mask[(size_t)t * BATCH + b];
  ltgt[t] = target[(size_t)t * BATCH + b];
  {
    const float4* src = (const float4*)(scores + (size_t)b * TT);
    float4 r0 = src[t]; float4 r1;
    if (t < 64) r1 = src[512 + t];
    float4* dst = (float4*)tile[0];
    dst[t] = r0;
    if (t < 64) dst[512 + t] = r1;
  }
  __syncthreads();
  float tg_local = 0.0f;
  for (int s = 0; s < S_LEN; ++s) {
    const int buf = s & 1;
    float4 r0, r1;
    if (s + 1 < S_LEN) {
      const float4* src = (const float4*)(scores + ((size_t)(s + 1) * BATCH + b) * TT);
      r0 = src[t];
      if (t < 64) r1 = src[512 + t];
    }
    if (s == 0) {
      if (t < T) p[t] = tile[0][START_TAG * T + t];
      if (t == 0 && lmask[0]) tg_local += tile[0][ltgt[0]];
    } else {
      if (valid) {
        const int i0 = ic * 6;
        float x[6]; float m = -1e30f;
#pragma unroll
        for (int kq = 0; kq < 6; ++kq) {
          x[kq] = tile[buf][(i0 + kq) * T + j] + p[i0 + kq];
          m = fmaxf(m, x[kq]);
        }
        float sum = 0.0f;
#pragma unroll
        for (int kq = 0; kq < 6; ++kq) sum += __expf(x[kq] - m);
        red_m[ic][j] = m; red_s[ic][j] = sum;
      }
      if (t == 0 && lmask[s]) tg_local += tile[buf][ltgt[s]];
    }
    __syncthreads();
    if (s > 0 && t < T) {
      float M = red_m[0][t];
#pragma unroll
      for (int g2 = 1; g2 < 8; ++g2) M = fmaxf(M, red_m[g2][t]);
      float Ssum = 0.0f;
#pragma unroll
      for (int g2 = 0; g2 < 8; ++g2) Ssum += red_s[g2][t] * __expf(red_m[g2][t] - M);
      float cur = M + __logf(Ssum);
      if (lmask[s]) p[t] = cur;
    }
    if (s + 1 < S_LEN) {
      float4* dst = (float4*)tile[buf ^ 1];
      dst[t] = r0;
      if (t < 64) dst[512 + t] = r1;
    }
    __syncthreads();
  }
  if (t == 0) ws[b] = p[END_TAG] - tg_local;
}

__global__ void fb_reduce(const float* __restrict__ ws, float* __restrict__ out)
{
  __shared__ float sh[BATCH];
  const int t = threadIdx.x;
  if (t < BATCH) sh[t] = ws[t];
  __syncthreads();
  if (t == 0) {
    float s = 0.0f;
    for (int k = 0; k < BATCH; ++k) s += sh[k];
    out[0] = s / (float)BATCH;
  }
}

extern "C" void kernel_launch(void* const* d_in, const int* in_sizes, int n_in,
                              void* d_out, int out_size, void* d_ws, size_t ws_size,
                              hipStream_t stream)
{
  const float* scores = (const float*)d_in[0];
  const int* target = (const int*)d_in[1];
  const int* mask = (const int*)d_in[2];
  float* out = (float*)d_out;

  const size_t RB_BYTES = (size_t)NTASK * TT * 2;  // bf16 chunk products
  const size_t need = RB_BYTES + (size_t)NTASK * 4 + (size_t)BATCH * 4;

  if (ws_size >= need) {
    unsigned short* Rbuf = (unsigned short*)d_ws;
    float* tgbuf = (float*)((char*)d_ws + RB_BYTES);
    float* vals = tgbuf + NTASK;
    crf_chunk<<<P1_BLOCKS, P1_THREADS, 0, stream>>>(scores, target, mask, Rbuf, tgbuf);
    crf_fold<<<BATCH, 64, 0, stream>>>(scores, Rbuf, tgbuf, vals);
    crf_final<<<1, 64, 0, stream>>>(vals, out);
  } else {
    float* ws = (float*)d_ws;
    fb_scan<<<BATCH, 512, 0, stream>>>(scores, target, mask, ws);
    fb_reduce<<<1, 128, 0, stream>>>(ws, out);
  }
}

// Round 11
// 119.985 us; speedup vs baseline: 1.1176x; 1.1176x over previous
//
#include <hip/hip_runtime.h>

// CRF loss forward, chunked log-semiring matrix-product formulation (register-direct v6).
// scores (512,128,48,48) f32, target (512,128) int32, mask (512,128) int32 -> scalar f32
//
// v6 = proven round-7 chunk kernel (121.5us, absmax 0.0) + proven round-8
//      fold/final simplification (fold absorbs tg; single-wave final).
//
// Phase 1: 2048 independent waves (CHUNK=32); wave (c,b) computes prod of 32
//   exp-space transition matrices from an EXACT identity B. K=48 split as
//   32 (mfma 16x16x32) + 16 (mfma 16x16x16). Per-step scale 2^-7 exact
//   (incl. identity steps) -> correction 512*7*ln2. Products stored bf16.
// Phase 2: per-batch fold of 16 bf16 chunk matrices (+ per-batch tg sum),
//   writes val_b = logZ_b - tg_b. Phase 3: single-wave 128-float reduce.

#define S_LEN 512
#define BATCH 128
#define T 48
#define TT 2304
#define START_TAG 46
#define END_TAG 47

#define CHUNK 32
#define NCHUNK 16
#define NTASK (NCHUNK * BATCH)       // 2048
#define P1_WAVES 4
#define P1_THREADS 256
#define P1_BLOCKS (NTASK / P1_WAVES) // 512
#define SIGMA 0.0078125f             // 2^-7

typedef float f32x4 __attribute__((ext_vector_type(4)));
typedef short bf16x8 __attribute__((ext_vector_type(8)));
typedef short bf16x4 __attribute__((ext_vector_type(4)));

__device__ __forceinline__ short f2bf(float x) {  // RTNE f32->bf16 bits
  unsigned u = __float_as_uint(x);
  u = (u + 0x7fffu + ((u >> 16) & 1u)) >> 16;
  return (short)u;
}

#if __has_builtin(__builtin_amdgcn_exp2f)
#define EXPS(x) __builtin_amdgcn_exp2f(fmaf((x), 1.44269504089f, -7.0f))
#else
#define EXPS(x) (__expf(x) * SIGMA)
#endif

#if __has_builtin(__builtin_amdgcn_mfma_f32_16x16x16bf16_1k)
#define MFMA16(a, b, c) __builtin_amdgcn_mfma_f32_16x16x16bf16_1k((a), (b), (c), 0, 0, 0)
#else
static __device__ __forceinline__ f32x4 mfma16_asm(bf16x4 a, bf16x4 b, f32x4 c) {
  f32x4 d;
  asm volatile("v_mfma_f32_16x16x16_bf16 %0, %1, %2, %3\n\ts_nop 7"
               : "=v"(d) : "v"(a), "v"(b), "v"(c));
  return d;
}
#define MFMA16(a, b, c) mfma16_asm((a), (b), (c))
#endif

struct Raw { float r24[24]; float r12[12]; };

// load matrix k's A-fragment raw f32 values (36/lane, coalesced 64B segments)
#define CRF_LOAD(RW, PE) do {                                                  \
  const float* q0_ = (PE) + (size_t)(8 * g) * T + c15;                         \
  _Pragma("unroll") for (int ti = 0; ti < 3; ++ti)                             \
    _Pragma("unroll") for (int i = 0; i < 8; ++i)                              \
      (RW).r24[ti * 8 + i] = q0_[(size_t)i * T + 16 * ti];                     \
  const float* q1_ = (PE) + (size_t)(32 + 4 * g) * T + c15;                    \
  _Pragma("unroll") for (int ti = 0; ti < 3; ++ti)                             \
    _Pragma("unroll") for (int i = 0; i < 4; ++i)                              \
      (RW).r12[ti * 4 + i] = q1_[(size_t)i * T + 16 * ti];                     \
} while (0)

// one product step: A = sigma*E^T (or sigma*I if masked or global step 0);
// Cf = A32.B32 + A16.B16; then recycle Cf -> (Bf32, Bf16).
#define CRF_STEP(RW, KK, RECYC) do {                                           \
  const int msk_ = __shfl(mt, (KK), 64);                                       \
  const bool id_ = (msk_ == 0) || ((s0 == 0) && ((KK) == 0));                  \
  bf16x8 A32_[3]; bf16x4 A16_[3];                                              \
  _Pragma("unroll") for (int ti = 0; ti < 3; ++ti) {                           \
    bf16x8 av_;                                                                \
    _Pragma("unroll") for (int i = 0; i < 8; ++i) {                            \
      float v_ = id_ ? (((8 * g + i) == (16 * ti + c15)) ? SIGMA : 0.f)        \
                     : EXPS((RW).r24[ti * 8 + i]);                             \
      av_[i] = f2bf(v_);                                                       \
    }                                                                          \
    A32_[ti] = av_;                                                            \
    bf16x4 aw_;                                                                \
    _Pragma("unroll") for (int i = 0; i < 4; ++i) {                            \
      float v_ = id_ ? (((32 + 4 * g + i) == (16 * ti + c15)) ? SIGMA : 0.f)   \
                     : EXPS((RW).r12[ti * 4 + i]);                             \
      aw_[i] = f2bf(v_);                                                       \
    }                                                                          \
    A16_[ti] = aw_;                                                            \
  }                                                                            \
  _Pragma("unroll") for (int ti = 0; ti < 3; ++ti)                             \
    _Pragma("unroll") for (int tj = 0; tj < 3; ++tj)                           \
      Cf[ti][tj] = __builtin_amdgcn_mfma_f32_16x16x32_bf16(A32_[ti], Bf32[tj], zz, 0, 0, 0); \
  _Pragma("unroll") for (int ti = 0; ti < 3; ++ti)                             \
    _Pragma("unroll") for (int tj = 0; tj < 3; ++tj)                           \
      Cf[ti][tj] = MFMA16(A16_[ti], Bf16[tj], Cf[ti][tj]);                     \
  if (RECYC) {                                                                 \
    _Pragma("unroll") for (int tj = 0; tj < 3; ++tj) {                         \
      bf16x8 b0_; bf16x4 b1_;                                                  \
      const int sLo_ = ((g & 1) << 5) + c15;                                   \
      _Pragma("unroll") for (int i = 0; i < 8; ++i) {                          \
        const int r_ = i & 3;                                                  \
        const int s_ = sLo_ + ((i & 4) ? 16 : 0);                              \
        float a0_ = __shfl(Cf[0][tj][r_], s_, 64);                             \
        float a1_ = __shfl(Cf[1][tj][r_], s_, 64);                             \
        b0_[i] = f2bf((g >> 1) ? a1_ : a0_);                                   \
      }                                                                        \
      _Pragma("unroll") for (int i = 0; i < 4; ++i) b1_[i] = f2bf(Cf[2][tj][i]); \
      Bf32[tj] = b0_; Bf16[tj] = b1_;                                          \
    }                                                                          \
  }                                                                            \
} while (0)

// ---------------- Phase 1: per-chunk matrix product ----------------
__global__ __launch_bounds__(P1_THREADS, 2) void crf_chunk(
    const float* __restrict__ scores, const int* __restrict__ target,
    const int* __restrict__ mask, unsigned short* __restrict__ Rbuf,
    float* __restrict__ tgbuf)
{
  const int t = threadIdx.x;
  const int lane = t & 63;
  const int wid = t >> 6;
  const int g = lane >> 4;    // 0..3
  const int c15 = lane & 15;  // 0..15

  const int task = blockIdx.x * P1_WAVES + wid;
  const int b = task & (BATCH - 1);
  const int cIdx = task >> 7;
  const int s0 = cIdx * CHUNK;

  // mask (lanes 0..31) / target (lanes 32..63) for this chunk, one reg
  int mt;
  {
    int sl = s0 + (lane & 31);
    mt = (lane < 32) ? mask[(size_t)sl * BATCH + b]
                     : target[(size_t)sl * BATCH + b];
  }

  // tg gather: lane k (k<32) loads scores[s0+k][b][tgt_k] -- all steps CONCURRENT
  float tg = 0.f;
  {
    int tgt_l = __shfl(mt, 32 + (lane & 31), 64);
    if (lane < CHUNK && mt)  // lane<32: mt == mask[s0+lane]
      tg = scores[((size_t)(s0 + lane) * BATCH + b) * TT + tgt_l];
  }

  const float* sb0 = scores + ((size_t)s0 * BATCH + b) * TT;
  const size_t mstride = (size_t)BATCH * TT;

  // prefetch raws for k=0 immediately
  Raw rA, rB;
  CRF_LOAD(rA, sb0);

  // ---- B init = EXACT identity (bf16 1.0 at kk==col)
  bf16x8 Bf32[3];
  bf16x4 Bf16[3];
#pragma unroll
  for (int tj = 0; tj < 3; ++tj) {
    const int col = 16 * tj + c15;
    bf16x8 bv;
#pragma unroll
    for (int i = 0; i < 8; ++i) bv[i] = ((8 * g + i) == col) ? (short)0x3F80 : (short)0;
    Bf32[tj] = bv;
    bf16x4 bw;
#pragma unroll
    for (int i = 0; i < 4; ++i) bw[i] = ((32 + 4 * g + i) == col) ? (short)0x3F80 : (short)0;
    Bf16[tj] = bw;
  }

  f32x4 Cf[3][3];
  const f32x4 zz = {0.f, 0.f, 0.f, 0.f};

  // software-pipelined x2: 32 steps total (k = 0..31)
  int k = 0;
#pragma unroll 1
  for (; k + 2 < CHUNK; k += 2) {
    CRF_LOAD(rB, sb0 + (size_t)(k + 1) * mstride);
    CRF_STEP(rA, k, 1);
    CRF_LOAD(rA, sb0 + (size_t)(k + 2) * mstride);
    CRF_STEP(rB, k + 1, 1);
  }
  // tail: steps 30, 31
  CRF_LOAD(rB, sb0 + (size_t)(CHUNK - 1) * mstride);
  CRF_STEP(rA, CHUNK - 2, 1);
  CRF_STEP(rB, CHUNK - 1, 0);

  // write chunk product R^T (48x48, row-major [j][i]) as bf16
  unsigned short* outp = Rbuf + (size_t)((size_t)cIdx * BATCH + b) * TT;
#pragma unroll
  for (int ti = 0; ti < 3; ++ti)
#pragma unroll
    for (int tj = 0; tj < 3; ++tj)
#pragma unroll
      for (int r = 0; r < 4; ++r) {
        int j = 16 * ti + 4 * g + r;
        int icol = 16 * tj + c15;
        outp[j * T + icol] = (unsigned short)f2bf(Cf[ti][tj][r]);
      }

  // reduce tg across lanes (lanes >= CHUNK hold 0)
#pragma unroll
  for (int d = 1; d < 64; d <<= 1) tg += __shfl_xor(tg, d, 64);
  if (lane == 0) tgbuf[task] = tg;
}

// ---------------- Phase 2: per-batch fold over 16 bf16 chunk matrices ----------------
// Also absorbs the per-batch tg reduction; writes val_b = logZ_b - tg_b.
__global__ __launch_bounds__(64) void crf_fold(
    const float* __restrict__ scores, const unsigned short* __restrict__ Rbuf,
    const float* __restrict__ tgbuf, float* __restrict__ vals)
{
  __shared__ __align__(16) float e[T];
  const int b = blockIdx.x;
  const int j = threadIdx.x & 63;
  const int jr = (j < T) ? j : (T - 1);
  float p = (j < T) ? scores[(size_t)b * TT + START_TAG * T + j] : -1e30f;

  // per-batch tg partial: lane c (c < NCHUNK) reads tgbuf[c*BATCH + b]
  float tgsum = (j < NCHUNK) ? tgbuf[(size_t)j * BATCH + b] : 0.f;

  // row j of chunk c: 48 bf16 = 96 B = 6 x uint4 (aligned: 4608*idx + 96*jr)
  uint4 bufA[6], bufB[6];
  {
    const uint4* rA = (const uint4*)(Rbuf + ((size_t)0 * BATCH + b) * TT + (size_t)jr * T);
#pragma unroll
    for (int q = 0; q < 6; ++q) bufA[q] = rA[q];
  }

#define FOLD_STEP(BUF) do {                                                    \
    float sh = __shfl(p, 0, 64);                                               \
    float ev = __expf(p - sh);                                                 \
    if (j < T) e[j] = ev;                                                      \
    asm volatile("s_waitcnt lgkmcnt(0)" ::: "memory");                         \
    __syncthreads();                                                           \
    float acc = 0.f;                                                           \
    _Pragma("unroll") for (int q = 0; q < 6; ++q) {                            \
      const unsigned* u = (const unsigned*)&(BUF)[q];                          \
      _Pragma("unroll") for (int h = 0; h < 4; ++h) {                          \
        float lo = __uint_as_float(u[h] << 16);                                \
        float hi = __uint_as_float(u[h] & 0xffff0000u);                        \
        acc += e[q * 8 + 2 * h] * lo;                                          \
        acc += e[q * 8 + 2 * h + 1] * hi;                                      \
      }                                                                        \
    }                                                                          \
    p = sh + __logf(acc);                                                      \
    __syncthreads();                                                           \
  } while (0)

#pragma unroll 1
  for (int c = 0; c < NCHUNK; c += 2) {
    const uint4* rB = (const uint4*)(Rbuf + ((size_t)(c + 1) * BATCH + b) * TT + (size_t)jr * T);
#pragma unroll
    for (int q = 0; q < 6; ++q) bufB[q] = rB[q];
    FOLD_STEP(bufA);
    if (c + 2 < NCHUNK) {
      const uint4* rA = (const uint4*)(Rbuf + ((size_t)(c + 2) * BATCH + b) * TT + (size_t)jr * T);
#pragma unroll
      for (int q = 0; q < 6; ++q) bufA[q] = rA[q];
    }
    FOLD_STEP(bufB);
  }
#undef FOLD_STEP

  // reduce tgsum across lanes (fixed order), fetch logZ from lane END_TAG
#pragma unroll
  for (int d = 1; d < 64; d <<= 1) tgsum += __shfl_xor(tgsum, d, 64);
  float pEnd = __shfl(p, END_TAG, 64);
  if (j == 0) vals[b] = pEnd - tgsum;
}

// ---------------- Phase 3: deterministic single-wave reduce ----------------
__global__ void crf_final(const float* __restrict__ vals, float* __restrict__ out)
{
  const int lane = threadIdx.x & 63;
  float v = vals[lane] + vals[64 + lane];
#pragma unroll
  for (int d = 1; d < 64; d <<= 1) v += __shfl_xor(v, d, 64);
  if (lane == 0) {
    // 512 steps, each scaled by exactly 2^-7 -> 512*7*ln2
    const float corr = 3584.0f * 0.6931471805599453f;
    out[0] = v / (float)BATCH + corr;
  }
}

// ---------------- Fallback (proven round-1 scan) for small ws ----------------
__global__ __launch_bounds__(512) void fb_scan(
    const float* __restrict__ scores, const int* __restrict__ target,
    const int* __restrict__ mask, float* __restrict__ ws)
{
  __shared__ float tile[2][TT];
  __shared__ float p[T];
  __shared__ float red_m[8][T];
  __shared__ float red_s[8][T];
  __shared__ int lmask[S_LEN];
  __shared__ int ltgt[S_LEN];

  const int b = blockIdx.x;
  const int t = threadIdx.x;
  const int j = t & 63;
  const int ic = t >> 6;
  const bool valid = (j < T);

  lmask[t] = mask[(size_t)t * BATCH + b];
  ltgt[t] = target[(size_t)t * BATCH + b];
  {
    const float4* src = (const float4*)(scores + (size_t)b * TT);
    float4 r0 = src[t]; float4 r1;
    if (t < 64) r1 = src[512 + t];
    float4* dst = (float4*)tile[0];
    dst[t] = r0;
    if (t < 64) dst[512 + t] = r1;
  }
  __syncthreads();
  float tg_local = 0.0f;
  for (int s = 0; s < S_LEN; ++s) {
    const int buf = s & 1;
    float4 r0, r1;
    if (s + 1 < S_LEN) {
      const float4* src = (const float4*)(scores + ((size_t)(s + 1) * BATCH + b) * TT);
      r0 = src[t];
      if (t < 64) r1 = src[512 + t];
    }
    if (s == 0) {
      if (t < T) p[t] = tile[0][START_TAG * T + t];
      if (t == 0 && lmask[0]) tg_local += tile[0][ltgt[0]];
    } else {
      if (valid) {
        const int i0 = ic * 6;
        float x[6]; float m = -1e30f;
#pragma unroll
        for (int kq = 0; kq < 6; ++kq) {
          x[kq] = tile[buf][(i0 + kq) * T + j] + p[i0 + kq];
          m = fmaxf(m, x[kq]);
        }
        float sum = 0.0f;
#pragma unroll
        for (int kq = 0; kq < 6; ++kq) sum += __expf(x[kq] - m);
        red_m[ic][j] = m; red_s[ic][j] = sum;
      }
      if (t == 0 && lmask[s]) tg_local += tile[buf][ltgt[s]];
    }
    __syncthreads();
    if (s > 0 && t < T) {
      float M = red_m[0][t];
#pragma unroll
      for (int g2 = 1; g2 < 8; ++g2) M = fmaxf(M, red_m[g2][t]);
      float Ssum = 0.0f;
#pragma unroll
      for (int g2 = 0; g2 < 8; ++g2) Ssum += red_s[g2][t] * __expf(red_m[g2][t] - M);
      float cur = M + __logf(Ssum);
      if (lmask[s]) p[t] = cur;
    }
    if (s + 1 < S_LEN) {
      float4* dst = (float4*)tile[buf ^ 1];
      dst[t] = r0;
      if (t < 64) dst[512 + t] = r1;
    }
    __syncthreads();
  }
  if (t == 0) ws[b] = p[END_TAG] - tg_local;
}

__global__ void fb_reduce(const float* __restrict__ ws, float* __restrict__ out)
{
  __shared__ float sh[BATCH];
  const int t = threadIdx.x;
  if (t < BATCH) sh[t] = ws[t];
  __syncthreads();
  if (t == 0) {
    float s = 0.0f;
    for (int k = 0; k < BATCH; ++k) s += sh[k];
    out[0] = s / (float)BATCH;
  }
}

extern "C" void kernel_launch(void* const* d_in, const int* in_sizes, int n_in,
                              void* d_out, int out_size, void* d_ws, size_t ws_size,
                              hipStream_t stream)
{
  const float* scores = (const float*)d_in[0];
  const int* target = (const int*)d_in[1];
  const int* mask = (const int*)d_in[2];
  float* out = (float*)d_out;

  const size_t RB_BYTES = (size_t)NTASK * TT * 2;  // bf16 chunk products
  const size_t need = RB_BYTES + (size_t)NTASK * 4 + (size_t)BATCH * 4;

  if (ws_size >= need) {
    unsigned short* Rbuf = (unsigned short*)d_ws;
    float* tgbuf = (float*)((char*)d_ws + RB_BYTES);
    float* vals = tgbuf + NTASK;
    crf_chunk<<<P1_BLOCKS, P1_THREADS, 0, stream>>>(scores, target, mask, Rbuf, tgbuf);
    crf_fold<<<BATCH, 64, 0, stream>>>(scores, Rbuf, tgbuf, vals);
    crf_final<<<1, 64, 0, stream>>>(vals, out);
  } else {
    float* ws = (float*)d_ws;
    fb_scan<<<BATCH, 512, 0, stream>>>(scores, target, mask, ws);
    fb_reduce<<<1, 128, 0, stream>>>(ws, out);
  }
}